// Round 2
// baseline (450.367 us; speedup 1.0000x reference)
//
#include <hip/hip_runtime.h>
#include <hip/hip_bf16.h>

#define NXX 256
#define T_INN 16
#define T_OUTT 128
#define NG (NXX * T_OUTT)        // 32768 nodes per batch
#define NBATCH 4
#define NNODES (NBATCH * NG)     // 131072
#define WID 128
#define NDEPTH 4

// ---------------------------------------------------------------------------
// Kernel 1: build X0 = feat @ W_in + b_in
// feat = [bilinear(u0), P(4), xg, tg]  (7 features), x-major node ordering
// ---------------------------------------------------------------------------
__global__ __launch_bounds__(128) void build_x_kernel(
    const float* __restrict__ u0, const float* __restrict__ P,
    const float* __restrict__ W_in, const float* __restrict__ b_in,
    float* __restrict__ X) {
    int n = blockIdx.x;          // global node id [0, NNODES)
    int c = threadIdx.x;         // channel [0, 128)
    int b = n >> 15;             // NG = 32768 = 2^15
    int u = n & (NG - 1);
    int i = u >> 7;              // x-major: i = u / T_OUT
    int t = u & 127;             // t = u % T_OUT

    // bilinear resize along t: 16 -> 128, half-pixel, edge clamp
    float s = (t + 0.5f) * (float)T_INN / (float)T_OUTT - 0.5f;
    float fs = floorf(s);
    int t0 = (int)fs;
    float w = s - fs;
    int t0c = t0 < 0 ? 0 : (t0 > T_INN - 1 ? T_INN - 1 : t0);
    int t1c = (t0 + 1) < 0 ? 0 : ((t0 + 1) > T_INN - 1 ? T_INN - 1 : (t0 + 1));
    const float* urow = u0 + ((size_t)b * NXX + i) * T_INN;
    float uv = urow[t0c] * (1.f - w) + urow[t1c] * w;

    float f0 = uv;
    float f1 = P[b * 4 + 0];
    float f2 = P[b * 4 + 1];
    float f3 = P[b * 4 + 2];
    float f4 = P[b * 4 + 3];
    float f5 = (float)i * (1.f / (float)(NXX - 1));
    float f6 = (float)t * (1.f / (float)(T_OUTT - 1));

    float acc = b_in[c];
    acc += f0 * W_in[0 * WID + c];
    acc += f1 * W_in[1 * WID + c];
    acc += f2 * W_in[2 * WID + c];
    acc += f3 * W_in[3 * WID + c];
    acc += f4 * W_in[4 * WID + c];
    acc += f5 * W_in[5 * WID + c];
    acc += f6 * W_in[6 * WID + c];
    X[(size_t)n * WID + c] = acc;
}

// ---------------------------------------------------------------------------
// Kernel 2: H = X @ W   (M x 128 @ 128 x 128), fp32 tiled
// block: 256 threads, tile 64 rows x 128 cols, 4x8 accumulators/thread
// ---------------------------------------------------------------------------
__global__ __launch_bounds__(256) void gemm_kernel(
    const float* __restrict__ X, const float* __restrict__ W,
    float* __restrict__ H) {
    __shared__ float Xs[64][129];   // +1 pad: kills bank conflict on col reads
    __shared__ float Ws[32][132];   // row stride 132 floats = 528B, 16B aligned

    int tid = threadIdx.x;
    int row0 = blockIdx.x * 64;
    int tx = tid & 15;   // col group: cols tx*8 .. tx*8+7
    int ty = tid >> 4;   // row group: rows ty*4 .. ty*4+3

    // load X tile: 64x128 floats, 8 float4 per thread, coalesced
#pragma unroll
    for (int it = 0; it < 8; ++it) {
        int idx = (it * 256 + tid) * 4;
        int r = idx >> 7;
        int c = idx & 127;
        float4 v = *reinterpret_cast<const float4*>(&X[(size_t)(row0 + r) * WID + c]);
        Xs[r][c] = v.x; Xs[r][c + 1] = v.y; Xs[r][c + 2] = v.z; Xs[r][c + 3] = v.w;
    }

    float acc[4][8];
#pragma unroll
    for (int i = 0; i < 4; ++i)
#pragma unroll
        for (int j = 0; j < 8; ++j) acc[i][j] = 0.f;

    for (int kc = 0; kc < 4; ++kc) {
        __syncthreads();   // protects Ws from previous iter + Xs stores (first iter)
        // load W rows [kc*32, kc*32+32): 4 float4 per thread
#pragma unroll
        for (int it = 0; it < 4; ++it) {
            int idx = (it * 256 + tid) * 4;
            int r = idx >> 7;
            int c = idx & 127;
            float4 v = *reinterpret_cast<const float4*>(&W[(size_t)(kc * 32 + r) * WID + c]);
            Ws[r][c] = v.x; Ws[r][c + 1] = v.y; Ws[r][c + 2] = v.z; Ws[r][c + 3] = v.w;
        }
        __syncthreads();
#pragma unroll
        for (int k = 0; k < 32; ++k) {
            float xv[4];
#pragma unroll
            for (int i = 0; i < 4; ++i) xv[i] = Xs[ty * 4 + i][kc * 32 + k];  // FIXED: global k
            float4 w0 = *reinterpret_cast<const float4*>(&Ws[k][tx * 8]);
            float4 w1 = *reinterpret_cast<const float4*>(&Ws[k][tx * 8 + 4]);
            float wv[8] = {w0.x, w0.y, w0.z, w0.w, w1.x, w1.y, w1.z, w1.w};
#pragma unroll
            for (int i = 0; i < 4; ++i)
#pragma unroll
                for (int j = 0; j < 8; ++j) acc[i][j] += xv[i] * wv[j];
        }
    }

#pragma unroll
    for (int i = 0; i < 4; ++i) {
        size_t r = (size_t)(row0 + ty * 4 + i) * WID;
#pragma unroll
        for (int j = 0; j < 8; j += 4) {
            float4 v = {acc[i][j], acc[i][j + 1], acc[i][j + 2], acc[i][j + 3]};
            *reinterpret_cast<float4*>(&H[r + tx * 8 + j]) = v;
        }
    }
}

// ---------------------------------------------------------------------------
// Kernel 3: per-layer epilogue. Due to the batch-mixing .view(2,-1) bug the
// graph reduces to:
//   batch 0,1 node u:  agg = h[u] + bg                      (deg = 1)
//   batch 2,3 node u:  agg = (2d/sqrt(2d+1))*h[u, batch-2] + h[u]/(2d+1) + bg
// where d = grid-neighbor count in t-major GRAPH indexing (i=u%256, t=u/256).
// Then LayerNorm(gamma,beta), x = relu(h + x) in place.
// One wave handles one pair ((b,u),(b+2,u)), lanes cover channels c, c+64.
// ---------------------------------------------------------------------------
__global__ __launch_bounds__(256) void layer_epilogue_kernel(
    const float* __restrict__ H, float* __restrict__ X,
    const float* __restrict__ bg, const float* __restrict__ gamma,
    const float* __restrict__ beta) {
    int gwid = (blockIdx.x * 256 + threadIdx.x) >> 6;  // pair id [0, 2*NG)
    int lane = threadIdx.x & 63;
    int b = gwid >> 15;            // 0 or 1
    int u = gwid & (NG - 1);

    // graph (t-major) position for degree
    int gi = u & (NXX - 1);
    int gt = u >> 8;
    int d = (gi > 0) + (gi < NXX - 1) + (gt > 0) + (gt < T_OUTT - 1);
    float deg = 2.f * (float)d + 1.f;
    float c1 = (2.f * (float)d) * rsqrtf(deg);
    float c2 = 1.f / deg;

    size_t r0 = ((size_t)b * NG + u) * WID;
    size_t r2 = ((size_t)(b + 2) * NG + u) * WID;

    float h0a = H[r0 + lane], h0b = H[r0 + lane + 64];
    float h2a = H[r2 + lane], h2b = H[r2 + lane + 64];
    float bga = bg[lane], bgb = bg[lane + 64];

    float a0a = h0a + bga,                 a0b = h0b + bgb;
    float a2a = c1 * h0a + c2 * h2a + bga, a2b = c1 * h0b + c2 * h2b + bgb;

    // LayerNorm both rows: wave-wide sums over 128 channels
    float s0 = a0a + a0b, q0 = a0a * a0a + a0b * a0b;
    float s2 = a2a + a2b, q2 = a2a * a2a + a2b * a2b;
#pragma unroll
    for (int m = 32; m > 0; m >>= 1) {
        s0 += __shfl_xor(s0, m);
        q0 += __shfl_xor(q0, m);
        s2 += __shfl_xor(s2, m);
        q2 += __shfl_xor(q2, m);
    }
    float mu0 = s0 * (1.f / WID), mu2 = s2 * (1.f / WID);
    float v0 = q0 * (1.f / WID) - mu0 * mu0;
    float v2 = q2 * (1.f / WID) - mu2 * mu2;
    float rs0 = rsqrtf(v0 + 1e-5f), rs2 = rsqrtf(v2 + 1e-5f);

    float ga = gamma[lane], gb = gamma[lane + 64];
    float ba = beta[lane],  bb = beta[lane + 64];

    float n0a = (a0a - mu0) * rs0 * ga + ba;
    float n0b = (a0b - mu0) * rs0 * gb + bb;
    float n2a = (a2a - mu2) * rs2 * ga + ba;
    float n2b = (a2b - mu2) * rs2 * gb + bb;

    float x0a = X[r0 + lane], x0b = X[r0 + lane + 64];
    float x2a = X[r2 + lane], x2b = X[r2 + lane + 64];

    X[r0 + lane]      = fmaxf(n0a + x0a, 0.f);
    X[r0 + lane + 64] = fmaxf(n0b + x0b, 0.f);
    X[r2 + lane]      = fmaxf(n2a + x2a, 0.f);
    X[r2 + lane + 64] = fmaxf(n2b + x2b, 0.f);
}

// ---------------------------------------------------------------------------
// Kernel 4: out = X @ W_out + b_out   (W_out is 128x1)
// one wave per node
// ---------------------------------------------------------------------------
__global__ __launch_bounds__(256) void out_kernel(
    const float* __restrict__ X, const float* __restrict__ W_out,
    const float* __restrict__ b_out, float* __restrict__ out) {
    int n = (blockIdx.x * 256 + threadIdx.x) >> 6;
    int lane = threadIdx.x & 63;
    size_t r = (size_t)n * WID;
    float v = X[r + lane] * W_out[lane] + X[r + lane + 64] * W_out[lane + 64];
#pragma unroll
    for (int m = 32; m > 0; m >>= 1) v += __shfl_xor(v, m);
    if (lane == 0) out[n] = v + b_out[0];
}

// ---------------------------------------------------------------------------
extern "C" void kernel_launch(void* const* d_in, const int* in_sizes, int n_in,
                              void* d_out, int out_size, void* d_ws, size_t ws_size,
                              hipStream_t stream) {
    const float* u0    = (const float*)d_in[0];
    const float* P     = (const float*)d_in[1];
    const float* W_in  = (const float*)d_in[2];
    const float* b_in  = (const float*)d_in[3];
    const float* Wg    = (const float*)d_in[4];
    const float* bg    = (const float*)d_in[5];
    const float* gamma = (const float*)d_in[6];
    const float* beta  = (const float*)d_in[7];
    const float* W_out = (const float*)d_in[8];
    const float* b_out = (const float*)d_in[9];

    float* X = (float*)d_ws;                              // NNODES x 128 f32
    float* H = X + (size_t)NNODES * WID;                  // NNODES x 128 f32
    float* out = (float*)d_out;

    build_x_kernel<<<NNODES, 128, 0, stream>>>(u0, P, W_in, b_in, X);

    for (int l = 0; l < NDEPTH; ++l) {
        gemm_kernel<<<NNODES / 64, 256, 0, stream>>>(
            X, Wg + (size_t)l * WID * WID, H);
        layer_epilogue_kernel<<<(2 * NG) / 4, 256, 0, stream>>>(
            H, X, bg + l * WID, gamma + l * WID, beta + l * WID);
    }

    out_kernel<<<NNODES / 4, 256, 0, stream>>>(X, W_out, b_out, out);
}

// Round 3
// 411.011 us; speedup vs baseline: 1.0958x; 1.0958x over previous
//
#include <hip/hip_runtime.h>
#include <hip/hip_bf16.h>

#define NXX 256
#define T_INN 16
#define T_OUTT 128
#define NG (NXX * T_OUTT)        // 32768 nodes per batch
#define WID 128
#define STR 132                  // LDS row stride in floats: 528B, 16B-aligned

// ---------------------------------------------------------------------------
// Fully-fused persistent kernel. The whole net is row-pair-local:
//   - H = X@W couples only within a row
//   - the batch-mixed graph couples only (b,u) <-> (b+2,u)   [b in {0,1}]
//   - LN is per-row
// Each block: 32 pairs (64 rows: 32 from batch b, 32 matching from b+2).
// x lives in registers (thread owns rows {2ty, 2ty+1} of both batches);
// LDS holds the 64x128 X tile (for the GEMM) + a 32x128 W chunk.
// ---------------------------------------------------------------------------
__global__ __launch_bounds__(256, 2) void fused_all_kernel(
    const float* __restrict__ u0, const float* __restrict__ P,
    const float* __restrict__ W_in, const float* __restrict__ b_in,
    const float* __restrict__ Wg, const float* __restrict__ bg,
    const float* __restrict__ gamma, const float* __restrict__ beta,
    const float* __restrict__ W_out, const float* __restrict__ b_out,
    float* __restrict__ out)
{
    __shared__ float Xs[64][STR];   // X tile, rows 0..31 = batch b, 32..63 = batch b+2
    __shared__ float Ws[32][STR];   // W k-chunk

    const int tid = threadIdx.x;
    const int tx  = tid & 15;       // col group: cols tx*8 .. tx*8+7
    const int ty  = tid >> 4;       // pair group: local u = 2ty, 2ty+1
    const int c0  = tx * 8;

    const int blk  = blockIdx.x;    // 0..2047
    const int b    = blk >> 10;     // batch 0 or 1 (partner is b+2)
    const int ublk = (blk & 1023) * 32;
    const int i_x  = ublk >> 7;     // x-major spatial index (same for whole block)
    const int tbas = ublk & 127;

    // ---- per-thread x rows: i=0 -> (b, 2ty), 1 -> (b, 2ty+1),
    //                          2 -> (b+2, 2ty), 3 -> (b+2, 2ty+1)
    float xr[4][8];

    // ======== build X0 = feat @ W_in + b_in ========
#pragma unroll
    for (int i = 0; i < 4; ++i) {
        const int lr = 2 * ty + (i & 1);
        const int bb = (i < 2) ? b : (b + 2);
        const int t  = tbas + lr;
        // bilinear 16 -> 128, half-pixel, edge clamp
        float s  = ((float)t + 0.5f) * 0.125f - 0.5f;
        float fs = floorf(s);
        int   t0 = (int)fs;
        float w  = s - fs;
        int t0c = t0 < 0 ? 0 : (t0 > 15 ? 15 : t0);
        int t1  = t0 + 1;
        int t1c = t1 < 0 ? 0 : (t1 > 15 ? 15 : t1);
        const float* urow = u0 + ((size_t)bb * NXX + i_x) * T_INN;
        float f0 = urow[t0c] * (1.f - w) + urow[t1c] * w;
        float f1 = P[bb * 4 + 0], f2 = P[bb * 4 + 1];
        float f3 = P[bb * 4 + 2], f4 = P[bb * 4 + 3];
        float f5 = (float)i_x * (1.f / 255.f);
        float f6 = (float)t   * (1.f / 127.f);
#pragma unroll
        for (int j = 0; j < 8; ++j) {
            int c = c0 + j;
            float a = b_in[c];
            a += f0 * W_in[0 * WID + c];
            a += f1 * W_in[1 * WID + c];
            a += f2 * W_in[2 * WID + c];
            a += f3 * W_in[3 * WID + c];
            a += f4 * W_in[4 * WID + c];
            a += f5 * W_in[5 * WID + c];
            a += f6 * W_in[6 * WID + c];
            xr[i][j] = a;
        }
    }

    // ---- graph-degree mixing coefficients (t-major indexing), per pair row
    float c1a, c2a, c1b, c2b;
    {
        int ua = ublk + 2 * ty;
        int gi = ua & 255, gt = ua >> 8;
        int d  = (gi > 0) + (gi < 255) + (gt > 0) + (gt < 127);
        float deg = 2.f * (float)d + 1.f;
        c1a = (2.f * (float)d) * rsqrtf(deg);
        c2a = 1.f / deg;
        int ub2 = ua + 1;
        gi = ub2 & 255; gt = ub2 >> 8;
        d  = (gi > 0) + (gi < 255) + (gt > 0) + (gt < 127);
        deg = 2.f * (float)d + 1.f;
        c1b = (2.f * (float)d) * rsqrtf(deg);
        c2b = 1.f / deg;
    }

    // write X0 tile to LDS
#pragma unroll
    for (int i = 0; i < 4; ++i) {
        int row = 2 * ty + (i & 1) + ((i >= 2) ? 32 : 0);
        float4* p = (float4*)&Xs[row][c0];
        p[0] = make_float4(xr[i][0], xr[i][1], xr[i][2], xr[i][3]);
        p[1] = make_float4(xr[i][4], xr[i][5], xr[i][6], xr[i][7]);
    }

    // ======== 4 GCN layers ========
    for (int l = 0; l < 4; ++l) {
        const float* wl = Wg + (size_t)l * WID * WID;
        float acc[4][8];
#pragma unroll
        for (int i = 0; i < 4; ++i)
#pragma unroll
            for (int j = 0; j < 8; ++j) acc[i][j] = 0.f;

        for (int kc = 0; kc < 4; ++kc) {
            __syncthreads();   // Ws consumed (and Xs writes visible at kc==0)
#pragma unroll
            for (int it = 0; it < 4; ++it) {
                int idx = (it * 256 + tid) * 4;
                int r = idx >> 7, c = idx & 127;
                float4 v = *(const float4*)(wl + (size_t)(kc * 32 + r) * WID + c);
                *(float4*)&Ws[r][c] = v;
            }
            __syncthreads();
            const int kb = kc * 32;
#pragma unroll
            for (int k4 = 0; k4 < 32; k4 += 4) {
                float4 va = *(const float4*)&Xs[2 * ty][kb + k4];
                float4 vb = *(const float4*)&Xs[2 * ty + 1][kb + k4];
                float4 vc = *(const float4*)&Xs[2 * ty + 32][kb + k4];
                float4 vd = *(const float4*)&Xs[2 * ty + 33][kb + k4];
                float xa[4] = {va.x, va.y, va.z, va.w};
                float xb[4] = {vb.x, vb.y, vb.z, vb.w};
                float xc[4] = {vc.x, vc.y, vc.z, vc.w};
                float xd[4] = {vd.x, vd.y, vd.z, vd.w};
#pragma unroll
                for (int kk = 0; kk < 4; ++kk) {
                    const float4 w0 = *(const float4*)&Ws[k4 + kk][c0];
                    const float4 w1 = *(const float4*)&Ws[k4 + kk][c0 + 4];
                    float wv[8] = {w0.x, w0.y, w0.z, w0.w, w1.x, w1.y, w1.z, w1.w};
#pragma unroll
                    for (int j = 0; j < 8; ++j) {
                        acc[0][j] += xa[kk] * wv[j];
                        acc[1][j] += xb[kk] * wv[j];
                        acc[2][j] += xc[kk] * wv[j];
                        acc[3][j] += xd[kk] * wv[j];
                    }
                }
            }
        }

        // ---- epilogue: mix pairs, +bg, LayerNorm, residual ReLU (all in regs)
        float a0[8], a1[8], a2[8], a3[8];
#pragma unroll
        for (int j = 0; j < 8; ++j) {
            float bgv = bg[l * WID + c0 + j];
            a0[j] = acc[0][j] + bgv;
            a1[j] = acc[1][j] + bgv;
            a2[j] = c1a * acc[0][j] + c2a * acc[2][j] + bgv;
            a3[j] = c1b * acc[1][j] + c2b * acc[3][j] + bgv;
        }
        float s0 = 0, q0 = 0, s1 = 0, q1 = 0, s2 = 0, q2 = 0, s3 = 0, q3 = 0;
#pragma unroll
        for (int j = 0; j < 8; ++j) {
            s0 += a0[j]; q0 += a0[j] * a0[j];
            s1 += a1[j]; q1 += a1[j] * a1[j];
            s2 += a2[j]; q2 += a2[j] * a2[j];
            s3 += a3[j]; q3 += a3[j] * a3[j];
        }
#pragma unroll
        for (int m = 1; m < 16; m <<= 1) {   // reduce over the 16 tx lanes
            s0 += __shfl_xor(s0, m); q0 += __shfl_xor(q0, m);
            s1 += __shfl_xor(s1, m); q1 += __shfl_xor(q1, m);
            s2 += __shfl_xor(s2, m); q2 += __shfl_xor(q2, m);
            s3 += __shfl_xor(s3, m); q3 += __shfl_xor(q3, m);
        }
        float mu0 = s0 * (1.f / WID), mu1 = s1 * (1.f / WID);
        float mu2 = s2 * (1.f / WID), mu3 = s3 * (1.f / WID);
        float rs0 = rsqrtf(q0 * (1.f / WID) - mu0 * mu0 + 1e-5f);
        float rs1 = rsqrtf(q1 * (1.f / WID) - mu1 * mu1 + 1e-5f);
        float rs2 = rsqrtf(q2 * (1.f / WID) - mu2 * mu2 + 1e-5f);
        float rs3 = rsqrtf(q3 * (1.f / WID) - mu3 * mu3 + 1e-5f);
#pragma unroll
        for (int j = 0; j < 8; ++j) {
            float g  = gamma[l * WID + c0 + j];
            float be = beta[l * WID + c0 + j];
            xr[0][j] = fmaxf((a0[j] - mu0) * rs0 * g + be + xr[0][j], 0.f);
            xr[1][j] = fmaxf((a1[j] - mu1) * rs1 * g + be + xr[1][j], 0.f);
            xr[2][j] = fmaxf((a2[j] - mu2) * rs2 * g + be + xr[2][j], 0.f);
            xr[3][j] = fmaxf((a3[j] - mu3) * rs3 * g + be + xr[3][j], 0.f);
        }

        if (l < 3) {
            __syncthreads();   // all GEMM reads of Xs done before overwrite
#pragma unroll
            for (int i = 0; i < 4; ++i) {
                int row = 2 * ty + (i & 1) + ((i >= 2) ? 32 : 0);
                float4* p = (float4*)&Xs[row][c0];
                p[0] = make_float4(xr[i][0], xr[i][1], xr[i][2], xr[i][3]);
                p[1] = make_float4(xr[i][4], xr[i][5], xr[i][6], xr[i][7]);
            }
        }
    }

    // ======== out head: out = x @ W_out + b_out, straight from registers ====
    float wo[8];
#pragma unroll
    for (int j = 0; j < 8; ++j) wo[j] = W_out[c0 + j];
    float bo = b_out[0];
#pragma unroll
    for (int i = 0; i < 4; ++i) {
        float p = 0.f;
#pragma unroll
        for (int j = 0; j < 8; ++j) p += xr[i][j] * wo[j];
#pragma unroll
        for (int m = 1; m < 16; m <<= 1) p += __shfl_xor(p, m);
        if (tx == 0) {
            int grow = ((i < 2) ? b : (b + 2)) * NG + ublk + 2 * ty + (i & 1);
            out[grow] = p + bo;
        }
    }
}

// ---------------------------------------------------------------------------
extern "C" void kernel_launch(void* const* d_in, const int* in_sizes, int n_in,
                              void* d_out, int out_size, void* d_ws, size_t ws_size,
                              hipStream_t stream) {
    const float* u0    = (const float*)d_in[0];
    const float* P     = (const float*)d_in[1];
    const float* W_in  = (const float*)d_in[2];
    const float* b_in  = (const float*)d_in[3];
    const float* Wg    = (const float*)d_in[4];
    const float* bg    = (const float*)d_in[5];
    const float* gamma = (const float*)d_in[6];
    const float* beta  = (const float*)d_in[7];
    const float* W_out = (const float*)d_in[8];
    const float* b_out = (const float*)d_in[9];

    fused_all_kernel<<<2048, 256, 0, stream>>>(
        u0, P, W_in, b_in, Wg, bg, gamma, beta, W_out, b_out, (float*)d_out);
}

// Round 4
// 106.653 us; speedup vs baseline: 4.2227x; 3.8537x over previous
//
#include <hip/hip_runtime.h>

#define NXX 256
#define NG 32768
#define WID 128

typedef short bf16x8 __attribute__((ext_vector_type(8)));
typedef float f32x4 __attribute__((ext_vector_type(4)));

__device__ __forceinline__ unsigned short rne_bf16(float x) {
    unsigned int u = __float_as_uint(x);
    return (unsigned short)((u + 0x7fffu + ((u >> 16) & 1u)) >> 16);
}
__device__ __forceinline__ float bf16_to_f(unsigned short h) {
    return __uint_as_float(((unsigned int)h) << 16);
}

// ---------------------------------------------------------------------------
// Prep: pack Wg (4 layers of [128 k][128 n] fp32) into B-fragment-linear bf16
// streams for mfma_f32_16x16x32_bf16.  B-frag layout: lane l holds
// B[kc*32 + (l>>4)*8 + j][nt*16 + (l&15)], j=0..7 contiguous (16B per lane).
// Stream index e = (l*4 + kc)*8 + nt, 512 bf16 per e.
// ---------------------------------------------------------------------------
__global__ __launch_bounds__(64) void prep_kernel(
    const float* __restrict__ Wg, unsigned short* __restrict__ Bfrag) {
    const int e  = blockIdx.x;       // 0..127
    const int lv = threadIdx.x;      // 0..63
    const int l  = e >> 5;
    const int kc = (e >> 3) & 3;
    const int nt = e & 7;
    const int n  = nt * 16 + (lv & 15);
    const int kb = kc * 32 + ((lv >> 4) << 3);
#pragma unroll
    for (int j = 0; j < 8; ++j) {
        float v = Wg[(size_t)l * 16384 + (size_t)(kb + j) * WID + n];
        Bfrag[(size_t)e * 512 + lv * 8 + j] = rne_bf16(v);
    }
}

// ---------------------------------------------------------------------------
// Fused net.  Block = 256 threads (4 waves), 64 tile rows, u-window of 32.
// Tile row tr = w*16 + m:  m<8 -> (batch b,  u=ublk+8w+m)
//                          m>=8 -> (batch b+2, u=ublk+8w+(m-8))
// Wave w computes its 16 rows x 128 cols per layer via 8 n-tiles of
// mfma_f32_16x16x32_bf16, K=128 in 4 chunks, split-A (hi+lo) x hi-B.
// X staged in LDS as hi/lo bf16 [64][128], XOR-swizzled (byte ^= (row&7)<<4).
// Degree mixing = shfl_xor(h,32); LN over 16-lane group; residual in regs.
// ---------------------------------------------------------------------------
__global__ __launch_bounds__(256) void fused_kernel(
    const float* __restrict__ u0, const float* __restrict__ P,
    const float* __restrict__ W_in, const float* __restrict__ b_in,
    const unsigned short* __restrict__ Bfrag,
    const float* __restrict__ bg, const float* __restrict__ gamma,
    const float* __restrict__ beta, const float* __restrict__ W_out,
    const float* __restrict__ b_out, float* __restrict__ out)
{
    __shared__ unsigned short XsH[64 * 128];   // 16 KB
    __shared__ unsigned short XsL[64 * 128];   // 16 KB

    const int tid  = threadIdx.x;
    const int w    = tid >> 6;       // wave 0..3
    const int lane = tid & 63;
    const int l15  = lane & 15;
    const int lhi  = lane >> 4;      // 0..3

    const int blk  = blockIdx.x;     // 0..2047
    const int b    = blk >> 10;      // 0 or 1; partner batch is b+2
    const int ublk = (blk & 1023) << 5;

    float c1v[4], c2v[4];            // degree-mixing coeffs (used by lanes>=32)
    float xres[8][4];                // residual x, D-layout [nt][reg]

    // ======== build X0 = feat @ W_in + b_in, directly in D-layout ========
    {
        float feat[4][7];
#pragma unroll
        for (int r = 0; r < 4; ++r) {
            const int m  = lhi * 4 + r;
            const int uo = m & 7;
            const int bb = b + ((m >> 3) << 1);
            const int u  = ublk + 8 * w + uo;
            const int ix = u >> 7, t = u & 127;
            // bilinear 16 -> 128, half-pixel, edge clamp
            float s  = ((float)t + 0.5f) * 0.125f - 0.5f;
            float fs = floorf(s);
            int   t0 = (int)fs;
            float wt = s - fs;
            int t0c = t0 < 0 ? 0 : (t0 > 15 ? 15 : t0);
            int t1n = t0 + 1;
            int t1c = t1n < 0 ? 0 : (t1n > 15 ? 15 : t1n);
            const float* ur = u0 + ((size_t)bb * NXX + ix) * 16;
            feat[r][0] = ur[t0c] * (1.f - wt) + ur[t1c] * wt;
            feat[r][1] = P[bb * 4 + 0];
            feat[r][2] = P[bb * 4 + 1];
            feat[r][3] = P[bb * 4 + 2];
            feat[r][4] = P[bb * 4 + 3];
            feat[r][5] = (float)ix * (1.f / 255.f);
            feat[r][6] = (float)t  * (1.f / 127.f);
            // graph degree (t-major indexing of u)
            int gi = u & 255, gt = u >> 8;
            int d  = (gi > 0) + (gi < 255) + (gt > 0) + (gt < 127);
            float deg = 2.f * (float)d + 1.f;
            c1v[r] = 2.f * (float)d * rsqrtf(deg);
            c2v[r] = 1.f / deg;
        }
#pragma unroll
        for (int nt = 0; nt < 8; ++nt) {
            const int c = nt * 16 + l15;
            float wi[7];
#pragma unroll
            for (int f = 0; f < 7; ++f) wi[f] = W_in[f * WID + c];
            const float bi = b_in[c];
#pragma unroll
            for (int r = 0; r < 4; ++r) {
                float a = bi;
#pragma unroll
                for (int f = 0; f < 7; ++f) a += feat[r][f] * wi[f];
                xres[nt][r] = a;
            }
        }
    }

    const char* xsh = (const char*)XsH;
    const char* xsl = (const char*)XsL;

    // ======== 4 GCN layers ========
    for (int l = 0; l < 4; ++l) {
        // ---- store x (hi/lo bf16) to LDS, swizzled, D-layout positions ----
#pragma unroll
        for (int nt = 0; nt < 8; ++nt) {
#pragma unroll
            for (int r = 0; r < 4; ++r) {
                const int m  = lhi * 4 + r;
                const int tr = w * 16 + m;
                const int c  = nt * 16 + l15;
                const int idx = ((tr * 256 + c * 2) ^ ((tr & 7) << 4)) >> 1;
                float v = xres[nt][r];
                unsigned short h = rne_bf16(v);
                XsH[idx] = h;
                XsL[idx] = rne_bf16(v - bf16_to_f(h));
            }
        }
        __syncthreads();

        // ---- load A fragments (wave-private rows) ----
        bf16x8 ah[4], al[4];
        {
            const int tr   = w * 16 + l15;    // A row = lane&15
            const int base = tr * 256;
            const int sw   = (tr & 7) << 4;
#pragma unroll
            for (int kc = 0; kc < 4; ++kc) {
                const int off = (base + kc * 64 + lhi * 16) ^ sw;
                ah[kc] = *(const bf16x8*)(xsh + off);
                al[kc] = *(const bf16x8*)(xsl + off);
            }
        }

        // ---- MFMA: acc[nt] = sum_kc (ah[kc] + al[kc]) * B[kc][nt] ----
        f32x4 acc[8];
        const unsigned short* bp = Bfrag + (size_t)l * 16384 + lane * 8;
#pragma unroll
        for (int nt = 0; nt < 8; ++nt) {
            f32x4 a = {0.f, 0.f, 0.f, 0.f};
#pragma unroll
            for (int kc = 0; kc < 4; ++kc) {
                bf16x8 bh = *(const bf16x8*)(bp + (kc * 8 + nt) * 512);
                a = __builtin_amdgcn_mfma_f32_16x16x32_bf16(ah[kc], bh, a, 0, 0, 0);
                a = __builtin_amdgcn_mfma_f32_16x16x32_bf16(al[kc], bh, a, 0, 0, 0);
            }
            acc[nt] = a;
        }

        // ---- epilogue: pair-mix, +bg, LayerNorm, residual ReLU ----
        float sres[4] = {0.f, 0.f, 0.f, 0.f};
        float qres[4] = {0.f, 0.f, 0.f, 0.f};
#pragma unroll
        for (int nt = 0; nt < 8; ++nt) {
            const float bgv = bg[l * WID + nt * 16 + l15];
#pragma unroll
            for (int r = 0; r < 4; ++r) {
                float h  = acc[nt][r];
                float pt = __shfl_xor(h, 32);   // partner batch value (same u)
                float a  = (lane >= 32) ? (c1v[r] * pt + c2v[r] * h + bgv)
                                        : (h + bgv);
                acc[nt][r] = a;
                sres[r] += a;
                qres[r] += a * a;
            }
        }
#pragma unroll
        for (int mm = 1; mm < 16; mm <<= 1) {
#pragma unroll
            for (int r = 0; r < 4; ++r) {
                sres[r] += __shfl_xor(sres[r], mm);
                qres[r] += __shfl_xor(qres[r], mm);
            }
        }
        float mu[4], rsg[4];
#pragma unroll
        for (int r = 0; r < 4; ++r) {
            mu[r]  = sres[r] * (1.f / 128.f);
            rsg[r] = rsqrtf(qres[r] * (1.f / 128.f) - mu[r] * mu[r] + 1e-5f);
        }
#pragma unroll
        for (int nt = 0; nt < 8; ++nt) {
            const int c = nt * 16 + l15;
            const float ga = gamma[l * WID + c];
            const float be = beta[l * WID + c];
#pragma unroll
            for (int r = 0; r < 4; ++r) {
                float nv = (acc[nt][r] - mu[r]) * rsg[r] * ga + be;
                xres[nt][r] = fmaxf(nv + xres[nt][r], 0.f);
            }
        }
        __syncthreads();   // Xs reads done before next layer's stores
    }

    // ======== out head: out = x @ W_out + b_out ========
    float wo[8];
#pragma unroll
    for (int nt = 0; nt < 8; ++nt) wo[nt] = W_out[nt * 16 + l15];
    const float bo = b_out[0];
#pragma unroll
    for (int r = 0; r < 4; ++r) {
        float p = 0.f;
#pragma unroll
        for (int nt = 0; nt < 8; ++nt) p += xres[nt][r] * wo[nt];
        p += __shfl_xor(p, 1);
        p += __shfl_xor(p, 2);
        p += __shfl_xor(p, 4);
        p += __shfl_xor(p, 8);
        if (l15 == 0) {
            const int m  = lhi * 4 + r;
            const int bb = b + ((m >> 3) << 1);
            const int u  = ublk + 8 * w + (m & 7);
            out[(size_t)bb * NG + u] = p + bo;
        }
    }
}

// ---------------------------------------------------------------------------
extern "C" void kernel_launch(void* const* d_in, const int* in_sizes, int n_in,
                              void* d_out, int out_size, void* d_ws, size_t ws_size,
                              hipStream_t stream) {
    const float* u0    = (const float*)d_in[0];
    const float* P     = (const float*)d_in[1];
    const float* W_in  = (const float*)d_in[2];
    const float* b_in  = (const float*)d_in[3];
    const float* Wg    = (const float*)d_in[4];
    const float* bg    = (const float*)d_in[5];
    const float* gamma = (const float*)d_in[6];
    const float* beta  = (const float*)d_in[7];
    const float* W_out = (const float*)d_in[8];
    const float* b_out = (const float*)d_in[9];

    unsigned short* Bfrag = (unsigned short*)d_ws;   // 4*4*8*512 bf16 = 128 KB

    prep_kernel<<<128, 64, 0, stream>>>(Wg, Bfrag);
    fused_kernel<<<2048, 256, 0, stream>>>(
        u0, P, W_in, b_in, Bfrag, bg, gamma, beta, W_out, b_out, (float*)d_out);
}

// Round 5
// 98.447 us; speedup vs baseline: 4.5747x; 1.0833x over previous
//
#include <hip/hip_runtime.h>
#include <hip/hip_bf16.h>

#define NXX 256
#define NG 32768
#define WID 128
#define STRW 68   // LDS row stride in u32 words (odd*4: 2-4 way banks, 16B-aligned)

typedef short bf16x8 __attribute__((ext_vector_type(8)));
typedef float f32x4 __attribute__((ext_vector_type(4)));

__device__ __forceinline__ unsigned short rne_bf16(float x) {
    unsigned int u = __float_as_uint(x);
    return (unsigned short)((u + 0x7fffu + ((u >> 16) & 1u)) >> 16);
}

// ---------------------------------------------------------------------------
// Prep: pack Wg (4 layers of [128 k][128 n] fp32) into fragment-linear bf16
// streams. Lane l of stream e=(l*4+kc)*8+nt holds W[kc*32+(l>>4)*8+j][nt*16+(l&15)].
// Used as the *A* operand of mfma (W^T tile): A[m'=l&15][k=(l>>4)*8+j].
// ---------------------------------------------------------------------------
__global__ __launch_bounds__(64) void prep_kernel(
    const float* __restrict__ Wg, unsigned short* __restrict__ Bfrag) {
    const int e  = blockIdx.x;       // 0..127
    const int lv = threadIdx.x;      // 0..63
    const int l  = e >> 5;
    const int kc = (e >> 3) & 3;
    const int nt = e & 7;
    const int n  = nt * 16 + (lv & 15);
    const int kb = kc * 32 + ((lv >> 4) << 3);
#pragma unroll
    for (int j = 0; j < 8; ++j) {
        float v = Wg[(size_t)l * 16384 + (size_t)(kb + j) * WID + n];
        Bfrag[(size_t)e * 512 + lv * 8 + j] = rne_bf16(v);
    }
}

__device__ __forceinline__ unsigned int pack_bf2(float a, float b) {
    union { __hip_bfloat162 h2; unsigned int u; } cv;
    cv.h2 = __float22bfloat162_rn(make_float2(a, b));   // low16 = a (even col)
    return cv.u;
}

// ---------------------------------------------------------------------------
// Fused net, swapped-operand MFMA: D = mfma(A=W^T-frag, B=X-frag) = H^T tile.
// Lane layout everywhere: row m = lane&15 (wave-private 16 rows), the thread
// owns cols {16nt + 4*(lane>>4) + r}. Rows m<8 -> batch b, m>=8 -> batch b+2,
// u = ublk + 8w + (m&7).  Partner mix = shfl_xor 8, LN reduce = shfl_xor 16,32.
// X staged per-wave in LDS as hi/lo bf16 pairs (u32), stride-68 rows.
// ---------------------------------------------------------------------------
__global__ __launch_bounds__(256) void fused_kernel(
    const float* __restrict__ u0, const float* __restrict__ P,
    const float* __restrict__ W_in, const float* __restrict__ b_in,
    const unsigned short* __restrict__ Bfrag,
    const float* __restrict__ bg, const float* __restrict__ gamma,
    const float* __restrict__ beta, const float* __restrict__ W_out,
    const float* __restrict__ b_out, float* __restrict__ out)
{
    __shared__ unsigned int XsH[4][16 * STRW];   // 17408 B
    __shared__ unsigned int XsL[4][16 * STRW];   // 17408 B

    const int tid  = threadIdx.x;
    const int w    = tid >> 6;
    const int lane = tid & 63;
    const int l15  = lane & 15;
    const int lhi  = lane >> 4;      // 0..3

    const int blk  = blockIdx.x;     // 0..2047
    const int b    = blk >> 10;      // 0 or 1; partner batch = b+2
    const int ublk = (blk & 1023) << 5;

    // ---- this lane's row ----
    const int uo  = l15 & 7;
    const int bb  = b + ((l15 >> 3) << 1);
    const int u   = ublk + 8 * w + uo;
    const int ix  = u >> 7;
    const int t   = u & 127;
    const bool isB2 = (l15 & 8) != 0;

    // degree coeffs (t-major graph indexing)
    float c1, c2;
    {
        int gi = u & 255, gt = u >> 8;
        int d  = (gi > 0) + (gi < 255) + (gt > 0) + (gt < 127);
        float deg = 2.f * (float)d + 1.f;
        c1 = 2.f * (float)d * rsqrtf(deg);
        c2 = 1.f / deg;
    }

    // ---- features of my row ----
    float feat[7];
    {
        float s  = ((float)t + 0.5f) * 0.125f - 0.5f;
        float fs = floorf(s);
        int   t0 = (int)fs;
        float wt = s - fs;
        int t0c = t0 < 0 ? 0 : (t0 > 15 ? 15 : t0);
        int t1n = t0 + 1;
        int t1c = t1n < 0 ? 0 : (t1n > 15 ? 15 : t1n);
        const float* ur = u0 + ((size_t)bb * NXX + ix) * 16;
        feat[0] = ur[t0c] * (1.f - wt) + ur[t1c] * wt;
        feat[1] = P[bb * 4 + 0];
        feat[2] = P[bb * 4 + 1];
        feat[3] = P[bb * 4 + 2];
        feat[4] = P[bb * 4 + 3];
        feat[5] = (float)ix * (1.f / 255.f);
        feat[6] = (float)t  * (1.f / 127.f);
    }

    // ---- X0 = feat @ W_in + b_in, directly in D-layout ----
    float xres[8][4];
#pragma unroll
    for (int nt = 0; nt < 8; ++nt) {
        const int c = nt * 16 + 4 * lhi;
        float4 bi4 = *(const float4*)(b_in + c);
        float4 wf[7];
#pragma unroll
        for (int f = 0; f < 7; ++f) wf[f] = *(const float4*)(W_in + f * WID + c);
#pragma unroll
        for (int r = 0; r < 4; ++r) {
            float a = ((const float*)&bi4)[r];
#pragma unroll
            for (int f = 0; f < 7; ++f) a += feat[f] * ((const float*)&wf[f])[r];
            xres[nt][r] = a;
        }
    }

    unsigned int* Hrow = &XsH[w][l15 * STRW];
    unsigned int* Lrow = &XsL[w][l15 * STRW];

    // ======== 4 GCN layers ========
    for (int l = 0; l < 4; ++l) {
        // ---- pack hi/lo and store (b64 per nt per buffer) ----
#pragma unroll
        for (int nt = 0; nt < 8; ++nt) {
            float x0 = xres[nt][0], x1 = xres[nt][1];
            float x2 = xres[nt][2], x3 = xres[nt][3];
            unsigned int p0 = pack_bf2(x0, x1);
            unsigned int p1 = pack_bf2(x2, x3);
            float h0 = __uint_as_float(p0 << 16);
            float h1 = __uint_as_float(p0 & 0xffff0000u);
            float h2 = __uint_as_float(p1 << 16);
            float h3 = __uint_as_float(p1 & 0xffff0000u);
            unsigned int q0 = pack_bf2(x0 - h0, x1 - h1);
            unsigned int q1 = pack_bf2(x2 - h2, x3 - h3);
            const int c2i = 8 * nt + 2 * lhi;
            *(uint2*)(Hrow + c2i) = make_uint2(p0, p1);
            *(uint2*)(Lrow + c2i) = make_uint2(q0, q1);
        }
        __syncthreads();

        // ---- read X fragments (B-operand layout: row l15, k = 32kc+8lhi+j) --
        bf16x8 xh[4], xl[4];
#pragma unroll
        for (int kc = 0; kc < 4; ++kc) {
            const int c2r = 16 * kc + 4 * lhi;
            xh[kc] = *(const bf16x8*)(Hrow + c2r);
            xl[kc] = *(const bf16x8*)(Lrow + c2r);
        }

        // ---- MFMA (swapped): acc[nt] = W^T-tile * (Xhi + Xlo) ----
        f32x4 acc[8];
        const unsigned short* bp = Bfrag + (size_t)l * 16384 + lane * 8;
#pragma unroll
        for (int nt = 0; nt < 8; ++nt) {
            f32x4 a = {0.f, 0.f, 0.f, 0.f};
#pragma unroll
            for (int kc = 0; kc < 4; ++kc) {
                bf16x8 bh = *(const bf16x8*)(bp + (kc * 8 + nt) * 512);
                a = __builtin_amdgcn_mfma_f32_16x16x32_bf16(bh, xh[kc], a, 0, 0, 0);
                a = __builtin_amdgcn_mfma_f32_16x16x32_bf16(bh, xl[kc], a, 0, 0, 0);
            }
            acc[nt] = a;
        }

        // ---- epilogue: pair mix (shfl 8), +bg, LN (per-row), residual ReLU --
        float s = 0.f, q = 0.f;
#pragma unroll
        for (int nt = 0; nt < 8; ++nt) {
            float4 bg4 = *(const float4*)(bg + l * WID + nt * 16 + 4 * lhi);
#pragma unroll
            for (int r = 0; r < 4; ++r) {
                float h  = acc[nt][r];
                float pt = __shfl_xor(h, 8);
                float bgr = ((const float*)&bg4)[r];
                float a  = isB2 ? (c1 * pt + c2 * h + bgr) : (h + bgr);
                acc[nt][r] = a;
                s += a;
                q += a * a;
            }
        }
        s += __shfl_xor(s, 16);  q += __shfl_xor(q, 16);
        s += __shfl_xor(s, 32);  q += __shfl_xor(q, 32);
        float mu = s * (1.f / 128.f);
        float rs = rsqrtf(q * (1.f / 128.f) - mu * mu + 1e-5f);
#pragma unroll
        for (int nt = 0; nt < 8; ++nt) {
            const int c = nt * 16 + 4 * lhi;
            float4 g4 = *(const float4*)(gamma + l * WID + c);
            float4 e4 = *(const float4*)(beta  + l * WID + c);
#pragma unroll
            for (int r = 0; r < 4; ++r) {
                float nv = (acc[nt][r] - mu) * rs * ((const float*)&g4)[r]
                           + ((const float*)&e4)[r];
                xres[nt][r] = fmaxf(nv + xres[nt][r], 0.f);
            }
        }
        __syncthreads();   // LDS reads of this layer done before next stores
    }

    // ======== out head ========
    float p = 0.f;
#pragma unroll
    for (int nt = 0; nt < 8; ++nt) {
        float4 wo4 = *(const float4*)(W_out + nt * 16 + 4 * lhi);
#pragma unroll
        for (int r = 0; r < 4; ++r) p += xres[nt][r] * ((const float*)&wo4)[r];
    }
    p += __shfl_xor(p, 16);
    p += __shfl_xor(p, 32);
    if (lhi == 0) out[(size_t)bb * NG + u] = p + b_out[0];
}

// ---------------------------------------------------------------------------
extern "C" void kernel_launch(void* const* d_in, const int* in_sizes, int n_in,
                              void* d_out, int out_size, void* d_ws, size_t ws_size,
                              hipStream_t stream) {
    const float* u0    = (const float*)d_in[0];
    const float* P     = (const float*)d_in[1];
    const float* W_in  = (const float*)d_in[2];
    const float* b_in  = (const float*)d_in[3];
    const float* Wg    = (const float*)d_in[4];
    const float* bg    = (const float*)d_in[5];
    const float* gamma = (const float*)d_in[6];
    const float* beta  = (const float*)d_in[7];
    const float* W_out = (const float*)d_in[8];
    const float* b_out = (const float*)d_in[9];

    unsigned short* Bfrag = (unsigned short*)d_ws;   // 128 KB

    prep_kernel<<<128, 64, 0, stream>>>(Wg, Bfrag);
    fused_kernel<<<2048, 256, 0, stream>>>(
        u0, P, W_in, b_in, Bfrag, bg, gamma, beta, W_out, b_out, (float*)d_out);
}

// Round 6
// 84.005 us; speedup vs baseline: 5.3612x; 1.1719x over previous
//
#include <hip/hip_runtime.h>
#include <hip/hip_bf16.h>

#define NXX 256
#define NG 32768
#define WID 128
#define STRW 68   // LDS row stride in u32 words (odd*4: 2-4 way banks, 16B-aligned)

typedef short bf16x8 __attribute__((ext_vector_type(8)));
typedef float f32x4 __attribute__((ext_vector_type(4)));

__device__ __forceinline__ unsigned short rne_bf16(float x) {
    unsigned int u = __float_as_uint(x);
    return (unsigned short)((u + 0x7fffu + ((u >> 16) & 1u)) >> 16);
}

// ---------------------------------------------------------------------------
// Prep: pack Wg (4 layers of [128 k][128 n] fp32) into fragment-linear bf16
// streams. Lane l of stream e=(l*4+kc)*8+nt holds W[kc*32+(l>>4)*8+j][nt*16+(l&15)].
// Used as the *A* operand of mfma (W^T tile): A[m'=l&15][k=(l>>4)*8+j].
// ---------------------------------------------------------------------------
__global__ __launch_bounds__(64) void prep_kernel(
    const float* __restrict__ Wg, unsigned short* __restrict__ Bfrag) {
    const int e  = blockIdx.x;       // 0..127
    const int lv = threadIdx.x;      // 0..63
    const int l  = e >> 5;
    const int kc = (e >> 3) & 3;
    const int nt = e & 7;
    const int n  = nt * 16 + (lv & 15);
    const int kb = kc * 32 + ((lv >> 4) << 3);
#pragma unroll
    for (int j = 0; j < 8; ++j) {
        float v = Wg[(size_t)l * 16384 + (size_t)(kb + j) * WID + n];
        Bfrag[(size_t)e * 512 + lv * 8 + j] = rne_bf16(v);
    }
}

__device__ __forceinline__ unsigned int pack_bf2(float a, float b) {
    union { __hip_bfloat162 h2; unsigned int u; } cv;
    cv.h2 = __float22bfloat162_rn(make_float2(a, b));   // low16 = a (even col)
    return cv.u;
}

// ---------------------------------------------------------------------------
// Fused net, swapped-operand MFMA: D = mfma(A=W^T-frag, B=X-frag) = H^T tile.
// Lane layout: row m = lane&15 (wave-private 16 rows), thread owns cols
// {16nt + 4*(lane>>4) + r}. Rows m<8 -> batch b, m>=8 -> batch b+2,
// u = ublk + 8w + (m&7).  Partner mix = shfl_xor 8, LN reduce = shfl_xor 16,32.
// X staged per-wave in PRIVATE LDS slices (XsH[w]/XsL[w]) -> NO barriers:
// waves drift independently so one wave's epilogue VALU hides another's
// MFMA/L2/shfl latency (m114 overlap). Within-wave DS ordering is enforced
// by the compiler's lgkmcnt insertion on the aliasing Hrow/Lrow accesses.
// ---------------------------------------------------------------------------
__global__ __launch_bounds__(256) void fused_kernel(
    const float* __restrict__ u0, const float* __restrict__ P,
    const float* __restrict__ W_in, const float* __restrict__ b_in,
    const unsigned short* __restrict__ Bfrag,
    const float* __restrict__ bg, const float* __restrict__ gamma,
    const float* __restrict__ beta, const float* __restrict__ W_out,
    const float* __restrict__ b_out, float* __restrict__ out)
{
    __shared__ unsigned int XsH[4][16 * STRW];   // 17408 B
    __shared__ unsigned int XsL[4][16 * STRW];   // 17408 B

    const int tid  = threadIdx.x;
    const int w    = tid >> 6;
    const int lane = tid & 63;
    const int l15  = lane & 15;
    const int lhi  = lane >> 4;      // 0..3

    const int blk  = blockIdx.x;     // 0..2047
    const int b    = blk >> 10;      // 0 or 1; partner batch = b+2
    const int ublk = (blk & 1023) << 5;

    // ---- this lane's row ----
    const int uo  = l15 & 7;
    const int bb  = b + ((l15 >> 3) << 1);
    const int u   = ublk + 8 * w + uo;
    const int ix  = u >> 7;
    const int t   = u & 127;
    const bool isB2 = (l15 & 8) != 0;

    // degree coeffs (t-major graph indexing)
    float c1, c2;
    {
        int gi = u & 255, gt = u >> 8;
        int d  = (gi > 0) + (gi < 255) + (gt > 0) + (gt < 127);
        float deg = 2.f * (float)d + 1.f;
        c1 = 2.f * (float)d * rsqrtf(deg);
        c2 = 1.f / deg;
    }

    // ---- features of my row ----
    float feat[7];
    {
        float s  = ((float)t + 0.5f) * 0.125f - 0.5f;
        float fs = floorf(s);
        int   t0 = (int)fs;
        float wt = s - fs;
        int t0c = t0 < 0 ? 0 : (t0 > 15 ? 15 : t0);
        int t1n = t0 + 1;
        int t1c = t1n < 0 ? 0 : (t1n > 15 ? 15 : t1n);
        const float* ur = u0 + ((size_t)bb * NXX + ix) * 16;
        feat[0] = ur[t0c] * (1.f - wt) + ur[t1c] * wt;
        feat[1] = P[bb * 4 + 0];
        feat[2] = P[bb * 4 + 1];
        feat[3] = P[bb * 4 + 2];
        feat[4] = P[bb * 4 + 3];
        feat[5] = (float)ix * (1.f / 255.f);
        feat[6] = (float)t  * (1.f / 127.f);
    }

    // ---- X0 = feat @ W_in + b_in, directly in D-layout ----
    float xres[8][4];
#pragma unroll
    for (int nt = 0; nt < 8; ++nt) {
        const int c = nt * 16 + 4 * lhi;
        float4 bi4 = *(const float4*)(b_in + c);
        float4 wf[7];
#pragma unroll
        for (int f = 0; f < 7; ++f) wf[f] = *(const float4*)(W_in + f * WID + c);
#pragma unroll
        for (int r = 0; r < 4; ++r) {
            float a = ((const float*)&bi4)[r];
#pragma unroll
            for (int f = 0; f < 7; ++f) a += feat[f] * ((const float*)&wf[f])[r];
            xres[nt][r] = a;
        }
    }

    unsigned int* Hrow = &XsH[w][l15 * STRW];
    unsigned int* Lrow = &XsL[w][l15 * STRW];

    // ======== 4 GCN layers (barrier-free) ========
    for (int l = 0; l < 4; ++l) {
        // ---- pack hi/lo and store (b64 per nt per buffer) ----
#pragma unroll
        for (int nt = 0; nt < 8; ++nt) {
            float x0 = xres[nt][0], x1 = xres[nt][1];
            float x2 = xres[nt][2], x3 = xres[nt][3];
            unsigned int p0 = pack_bf2(x0, x1);
            unsigned int p1 = pack_bf2(x2, x3);
            float h0 = __uint_as_float(p0 << 16);
            float h1 = __uint_as_float(p0 & 0xffff0000u);
            float h2 = __uint_as_float(p1 << 16);
            float h3 = __uint_as_float(p1 & 0xffff0000u);
            unsigned int q0 = pack_bf2(x0 - h0, x1 - h1);
            unsigned int q1 = pack_bf2(x2 - h2, x3 - h3);
            const int c2i = 8 * nt + 2 * lhi;
            *(uint2*)(Hrow + c2i) = make_uint2(p0, p1);
            *(uint2*)(Lrow + c2i) = make_uint2(q0, q1);
        }

        // ---- read X fragments (B-operand layout: row l15, k = 32kc+8lhi+j) --
        bf16x8 xh[4], xl[4];
#pragma unroll
        for (int kc = 0; kc < 4; ++kc) {
            const int c2r = 16 * kc + 4 * lhi;
            xh[kc] = *(const bf16x8*)(Hrow + c2r);
            xl[kc] = *(const bf16x8*)(Lrow + c2r);
        }

        // ---- MFMA (swapped): acc[nt] = W^T-tile * (Xhi + Xlo) ----
        f32x4 acc[8];
        const unsigned short* bp = Bfrag + (size_t)l * 16384 + lane * 8;
#pragma unroll
        for (int nt = 0; nt < 8; ++nt) {
            f32x4 a = {0.f, 0.f, 0.f, 0.f};
#pragma unroll
            for (int kc = 0; kc < 4; ++kc) {
                bf16x8 bh = *(const bf16x8*)(bp + (kc * 8 + nt) * 512);
                a = __builtin_amdgcn_mfma_f32_16x16x32_bf16(bh, xh[kc], a, 0, 0, 0);
                a = __builtin_amdgcn_mfma_f32_16x16x32_bf16(bh, xl[kc], a, 0, 0, 0);
            }
            acc[nt] = a;
        }

        // ---- epilogue: pair mix (shfl 8), +bg, LN (per-row), residual ReLU --
        float s = 0.f, q = 0.f;
#pragma unroll
        for (int nt = 0; nt < 8; ++nt) {
            float4 bg4 = *(const float4*)(bg + l * WID + nt * 16 + 4 * lhi);
#pragma unroll
            for (int r = 0; r < 4; ++r) {
                float h  = acc[nt][r];
                float pt = __shfl_xor(h, 8);
                float bgr = ((const float*)&bg4)[r];
                float a  = isB2 ? (c1 * pt + c2 * h + bgr) : (h + bgr);
                acc[nt][r] = a;
                s += a;
                q += a * a;
            }
        }
        s += __shfl_xor(s, 16);  q += __shfl_xor(q, 16);
        s += __shfl_xor(s, 32);  q += __shfl_xor(q, 32);
        float mu = s * (1.f / 128.f);
        float rs = rsqrtf(q * (1.f / 128.f) - mu * mu + 1e-5f);
#pragma unroll
        for (int nt = 0; nt < 8; ++nt) {
            const int c = nt * 16 + 4 * lhi;
            float4 g4 = *(const float4*)(gamma + l * WID + c);
            float4 e4 = *(const float4*)(beta  + l * WID + c);
#pragma unroll
            for (int r = 0; r < 4; ++r) {
                float nv = (acc[nt][r] - mu) * rs * ((const float*)&g4)[r]
                           + ((const float*)&e4)[r];
                xres[nt][r] = fmaxf(nv + xres[nt][r], 0.f);
            }
        }
        // no barrier: next layer's stores only touch this wave's own LDS rows,
        // ordered after this layer's reads by within-wave DS dependencies.
    }

    // ======== out head ========
    float p = 0.f;
#pragma unroll
    for (int nt = 0; nt < 8; ++nt) {
        float4 wo4 = *(const float4*)(W_out + nt * 16 + 4 * lhi);
#pragma unroll
        for (int r = 0; r < 4; ++r) p += xres[nt][r] * ((const float*)&wo4)[r];
    }
    p += __shfl_xor(p, 16);
    p += __shfl_xor(p, 32);
    if (lhi == 0) out[(size_t)bb * NG + u] = p + b_out[0];
}

// ---------------------------------------------------------------------------
extern "C" void kernel_launch(void* const* d_in, const int* in_sizes, int n_in,
                              void* d_out, int out_size, void* d_ws, size_t ws_size,
                              hipStream_t stream) {
    const float* u0    = (const float*)d_in[0];
    const float* P     = (const float*)d_in[1];
    const float* W_in  = (const float*)d_in[2];
    const float* b_in  = (const float*)d_in[3];
    const float* Wg    = (const float*)d_in[4];
    const float* bg    = (const float*)d_in[5];
    const float* gamma = (const float*)d_in[6];
    const float* beta  = (const float*)d_in[7];
    const float* W_out = (const float*)d_in[8];
    const float* b_out = (const float*)d_in[9];

    unsigned short* Bfrag = (unsigned short*)d_ws;   // 128 KB

    prep_kernel<<<128, 64, 0, stream>>>(Wg, Bfrag);
    fused_kernel<<<2048, 256, 0, stream>>>(
        u0, P, W_in, b_in, Bfrag, bg, gamma, beta, W_out, b_out, (float*)d_out);
}